// Round 3
// baseline (231.812 us; speedup 1.0000x reference)
//
#include <hip/hip_runtime.h>
#include <hip/hip_bf16.h>

// Shapes (fixed): B=2048, S=50, D=128, H=8, L=128, HL=1024.
// R3: weight-stationary fused kernel. Block=(head, 8 batches), 4 waves.
// Wave holds its 32 columns of Wq/Wv as register-resident MFMA B-frags.
// x double-buffered in XOR-swizzled LDS; sigmoid = rcp(1+exp2(pre-scaled)).

typedef _Float16 f16x8 __attribute__((ext_vector_type(8)));
typedef float f32x4 __attribute__((ext_vector_type(4)));

#define LOG2E 1.44269504088896340736f
#define GBATCH 8

__device__ __forceinline__ unsigned short f2h(float f) {
  _Float16 h = (_Float16)f;
  return __builtin_bit_cast(unsigned short, h);
}
__device__ __forceinline__ float h2f(unsigned short s) {
  return (float)__builtin_bit_cast(_Float16, s);
}
__device__ __forceinline__ float fexp2(float x) {
#if __has_builtin(__builtin_amdgcn_exp2f)
  return __builtin_amdgcn_exp2f(x);
#else
  return exp2f(x);
#endif
}
__device__ __forceinline__ float frcp(float x) {
#if __has_builtin(__builtin_amdgcn_rcpf)
  return __builtin_amdgcn_rcpf(x);
#else
  return 1.0f / x;
#endif
}
__device__ __forceinline__ float sig_scaled(float a) {  // a = -log2e * z
  return frcp(1.0f + fexp2(a));
}

// ---------------------------------------------------------------------------
// prep: WqT/WkT/WvT [n=h*128+l][d] and OT [d][hl], all fp16, scaled by -log2e
// ---------------------------------------------------------------------------
__global__ void prep_kernel(const float* __restrict__ Wq, const float* __restrict__ Wk,
                            const float* __restrict__ Wv, const float* __restrict__ O,
                            unsigned short* __restrict__ ws16) {
  const float NS = -LOG2E;
  int tid = blockIdx.x * 256 + threadIdx.x;
  for (int j = tid; j < 4 * 131072; j += 512 * 256) {
    int which = j >> 17;
    int i = j & 131071;
    float val;
    if (which < 3) {
      const float* W = (which == 0) ? Wq : ((which == 1) ? Wk : Wv);
      int n = i >> 7, d = i & 127;
      int h = n >> 7, lidx = n & 127;
      val = W[h * 16384 + d * 128 + lidx];
    } else {
      int n = i >> 10, k = i & 1023;
      val = O[k * 128 + n];
    }
    ws16[j] = f2h(val * NS);
  }
}

// ---------------------------------------------------------------------------
// kw_all[b][n] = sigmoid(origin_b . Wk[:,n]) * Ws_flat[n]   (fp16)
// ---------------------------------------------------------------------------
__global__ __launch_bounds__(256, 2) void kw_kernel(
    const float* __restrict__ x, const float* __restrict__ Ws,
    const unsigned short* __restrict__ WkT, unsigned short* __restrict__ kw_all) {
  __shared__ __align__(16) char lds[16384];
  const int tid = threadIdx.x;
  const int b0 = blockIdx.x * 64;
  for (int i = tid; i < 2048; i += 256) {
    int row = i >> 5, c4 = i & 31;
    const float4 v = *(const float4*)(x + (size_t)(b0 + row) * 6400 + c4 * 4);
    uint2 pk;
    pk.x = (unsigned)f2h(v.x) | ((unsigned)f2h(v.y) << 16);
    pk.y = (unsigned)f2h(v.z) | ((unsigned)f2h(v.w) << 16);
    *(uint2*)(lds + row * 256 + ((c4 * 8) ^ ((row & 7) << 4))) = pk;
  }
  __syncthreads();
  const int w = tid >> 6, l = tid & 63, l15 = l & 15, l4 = l >> 4;
  f16x8 af[4][4];
#pragma unroll
  for (int mt = 0; mt < 4; ++mt)
#pragma unroll
    for (int kt = 0; kt < 4; ++kt) {
      int row = mt * 16 + l15;
      int c = kt * 64 + l4 * 16;
      af[mt][kt] = *(const f16x8*)(lds + row * 256 + (c ^ ((row & 7) << 4)));
    }
  const f16x8* B8 = (const f16x8*)WkT;
  for (int nt = 0; nt < 4; ++nt) {
    const int n0 = blockIdx.y * 256 + w * 64 + nt * 16;
    f16x8 bfr[4];
#pragma unroll
    for (int kt = 0; kt < 4; ++kt) bfr[kt] = B8[(size_t)(n0 + l15) * 16 + kt * 4 + l4];
    f32x4 acc[4];
#pragma unroll
    for (int mt = 0; mt < 4; ++mt) acc[mt] = (f32x4){0.f, 0.f, 0.f, 0.f};
#pragma unroll
    for (int mt = 0; mt < 4; ++mt)
#pragma unroll
      for (int kt = 0; kt < 4; ++kt)
        acc[mt] = __builtin_amdgcn_mfma_f32_16x16x32_f16(af[mt][kt], bfr[kt], acc[mt], 0, 0, 0);
    const float wsv = Ws[n0 + l15];
#pragma unroll
    for (int mt = 0; mt < 4; ++mt)
#pragma unroll
      for (int r = 0; r < 4; ++r) {
        int row = b0 + mt * 16 + l4 * 4 + r;
        kw_all[(size_t)row * 1024 + n0 + l15] = f2h(sig_scaled(acc[mt][r]) * wsv);
      }
  }
}

// ---------------------------------------------------------------------------
// fused: block=(head h, 8 batches). Wave owns 32 cols of head; Wq/Wv frags
// register-resident. Per batch: Q->score->softmax->V->res.
// ---------------------------------------------------------------------------
__global__ __launch_bounds__(256, 2) void fused_kernel(
    const float* __restrict__ x,
    const unsigned short* __restrict__ WqT, const unsigned short* __restrict__ WvT,
    const unsigned short* __restrict__ kw_all, unsigned short* __restrict__ res_all) {
  __shared__ __align__(16) char xlds[2][16384];
  __shared__ float score_lds[4][64];
  __shared__ float attn_lds[4][64];
  const int tid = threadIdx.x;
  const int w = tid >> 6, l = tid & 63, l15 = l & 15, l4 = l >> 4;
  const int h = blockIdx.x;                 // 0..7
  const int g0 = blockIdx.y * GBATCH;       // batch group start
  const int ncol = h * 128 + w * 32;        // wave's first column (flat n)

  // ---- weight fragments, register-resident for the whole block ----
  const f16x8* Bq8 = (const f16x8*)WqT;
  const f16x8* Bv8 = (const f16x8*)WvT;
  f16x8 wq[2][4], wv[2][4];
#pragma unroll
  for (int nt = 0; nt < 2; ++nt)
#pragma unroll
    for (int kt = 0; kt < 4; ++kt) {
      size_t base = (size_t)(ncol + nt * 16 + l15) * 16 + kt * 4 + l4;
      wq[nt][kt] = Bq8[base];
      wv[nt][kt] = Bv8[base];
    }

  // ---- zero pad rows (50..63) of both buffers, once ----
  for (int idx = tid; idx < 448; idx += 256) {
    int row = 50 + (idx >> 5), c4 = idx & 31;
    uint2 z = {0u, 0u};
    *(uint2*)(xlds[0] + row * 256 + ((c4 * 8) ^ ((row & 7) << 4))) = z;
    *(uint2*)(xlds[1] + row * 256 + ((c4 * 8) ^ ((row & 7) << 4))) = z;
  }
  // ---- stage first batch into buf0 ----
  {
    const float* xb = x + (size_t)g0 * 6400;
#pragma unroll
    for (int j = 0; j < 7; ++j) {
      int idx = tid + j * 256;
      if (idx < 1600) {
        float4 v = *(const float4*)(xb + idx * 4);
        int row = idx >> 5, c4 = idx & 31;
        uint2 pk;
        pk.x = (unsigned)f2h(v.x) | ((unsigned)f2h(v.y) << 16);
        pk.y = (unsigned)f2h(v.z) | ((unsigned)f2h(v.w) << 16);
        *(uint2*)(xlds[0] + row * 256 + ((c4 * 8) ^ ((row & 7) << 4))) = pk;
      }
    }
  }
  __syncthreads();

  for (int i = 0; i < GBATCH; ++i) {
    const int b = g0 + i;
    const char* cur = xlds[i & 1];
    char* nxt = xlds[(i + 1) & 1];

    // -- issue next-batch global loads early (hidden under compute) --
    float4 xr[7];
    if (i + 1 < GBATCH) {
      const float* xn = x + (size_t)(b + 1) * 6400;
#pragma unroll
      for (int j = 0; j < 7; ++j) {
        int idx = tid + j * 256;
        if (idx < 1600) xr[j] = *(const float4*)(xn + idx * 4);
      }
    }
    // -- kw for this wave's 32 cols --
    const float kw0 = h2f(kw_all[(size_t)b * 1024 + ncol + l15]);
    const float kw1 = h2f(kw_all[(size_t)b * 1024 + ncol + 16 + l15]);

    // -- A-frags (x) from LDS, live through both passes --
    f16x8 af[4][4];
#pragma unroll
    for (int mt = 0; mt < 4; ++mt)
#pragma unroll
      for (int kt = 0; kt < 4; ++kt) {
        int row = mt * 16 + l15;
        int c = kt * 64 + l4 * 16;
        af[mt][kt] = *(const f16x8*)(cur + row * 256 + (c ^ ((row & 7) << 4)));
      }

    // ---- Q pass: score partials over this wave's 32 cols ----
    float sAcc[4][4];
#pragma unroll
    for (int mt = 0; mt < 4; ++mt)
#pragma unroll
      for (int r = 0; r < 4; ++r) sAcc[mt][r] = 0.f;
#pragma unroll
    for (int nt = 0; nt < 2; ++nt) {
      f32x4 acc[4];
#pragma unroll
      for (int mt = 0; mt < 4; ++mt) acc[mt] = (f32x4){0.f, 0.f, 0.f, 0.f};
#pragma unroll
      for (int kt = 0; kt < 4; ++kt)
#pragma unroll
        for (int mt = 0; mt < 4; ++mt)
          acc[mt] = __builtin_amdgcn_mfma_f32_16x16x32_f16(af[mt][kt], wq[nt][kt], acc[mt], 0, 0, 0);
      const float kwv = (nt == 0) ? kw0 : kw1;
#pragma unroll
      for (int mt = 0; mt < 4; ++mt)
#pragma unroll
        for (int r = 0; r < 4; ++r)
          sAcc[mt][r] = fmaf(sig_scaled(acc[mt][r]), kwv, sAcc[mt][r]);
    }
    // reduce over the 16 cols held across l15 lanes
#pragma unroll
    for (int mt = 0; mt < 4; ++mt)
#pragma unroll
      for (int r = 0; r < 4; ++r) {
        float v = sAcc[mt][r];
        v += __shfl_xor(v, 1);
        v += __shfl_xor(v, 2);
        v += __shfl_xor(v, 4);
        v += __shfl_xor(v, 8);
        if (l15 == 0) score_lds[w][mt * 16 + l4 * 4 + r] = v;
      }
    __syncthreads();

    // ---- softmax over s, redundant per wave (lane = s) ----
    {
      float s = (l < 50)
                    ? (score_lds[0][l] + score_lds[1][l] + score_lds[2][l] + score_lds[3][l])
                    : -3.0e38f;
      float m = s;
#pragma unroll
      for (int d = 1; d < 64; d <<= 1) m = fmaxf(m, __shfl_xor(m, d));
      float e = (l < 50) ? fexp2((s - m) * LOG2E) : 0.f;
      float t = e;
#pragma unroll
      for (int d = 1; d < 64; d <<= 1) t += __shfl_xor(t, d);
      attn_lds[w][l] = e * frcp(t);  // own slice: no cross-wave barrier needed
    }
    float at[4][4];
#pragma unroll
    for (int mt = 0; mt < 4; ++mt)
#pragma unroll
      for (int r = 0; r < 4; ++r) at[mt][r] = attn_lds[w][mt * 16 + l4 * 4 + r];

    // ---- V pass: res[col] = sum_s attn[s] * sigmoid(v[s,col]) ----
    float part0 = 0.f, part1 = 0.f;
#pragma unroll
    for (int nt = 0; nt < 2; ++nt) {
      f32x4 acc[4];
#pragma unroll
      for (int mt = 0; mt < 4; ++mt) acc[mt] = (f32x4){0.f, 0.f, 0.f, 0.f};
#pragma unroll
      for (int kt = 0; kt < 4; ++kt)
#pragma unroll
        for (int mt = 0; mt < 4; ++mt)
          acc[mt] = __builtin_amdgcn_mfma_f32_16x16x32_f16(af[mt][kt], wv[nt][kt], acc[mt], 0, 0, 0);
      float p = 0.f;
#pragma unroll
      for (int mt = 0; mt < 4; ++mt)
#pragma unroll
        for (int r = 0; r < 4; ++r)
          p = fmaf(at[mt][r], sig_scaled(acc[mt][r]), p);
      if (nt == 0) part0 = p; else part1 = p;
    }
    part0 += __shfl_xor(part0, 16);
    part0 += __shfl_xor(part0, 32);
    part1 += __shfl_xor(part1, 16);
    part1 += __shfl_xor(part1, 32);
    if (l < 16) {
      res_all[(size_t)b * 1024 + ncol + l] = f2h(part0);
      res_all[(size_t)b * 1024 + ncol + 16 + l] = f2h(part1);
    }

    // ---- write staged next batch into nxt ----
    if (i + 1 < GBATCH) {
#pragma unroll
      for (int j = 0; j < 7; ++j) {
        int idx = tid + j * 256;
        if (idx < 1600) {
          int row = idx >> 5, c4 = idx & 31;
          uint2 pk;
          pk.x = (unsigned)f2h(xr[j].x) | ((unsigned)f2h(xr[j].y) << 16);
          pk.y = (unsigned)f2h(xr[j].z) | ((unsigned)f2h(xr[j].w) << 16);
          *(uint2*)(nxt + row * 256 + ((c4 * 8) ^ ((row & 7) << 4))) = pk;
        }
      }
    }
    __syncthreads();
  }
}

// ---------------------------------------------------------------------------
// out[b][d] = sigmoid(res[b,:] . O[:,d]) + x[b][0][d]
// ---------------------------------------------------------------------------
__global__ __launch_bounds__(256, 4) void out_kernel(
    const unsigned short* __restrict__ res_all, const unsigned short* __restrict__ OT,
    const float* __restrict__ x, float* __restrict__ out) {
  const int tid = threadIdx.x;
  const int w = tid >> 6, l = tid & 63, l15 = l & 15, l4 = l >> 4;
  const int b0 = blockIdx.x * 16;
  const f16x8* A8 = (const f16x8*)res_all;
  const f16x8* B8 = (const f16x8*)OT;
  f32x4 acc0 = (f32x4){0.f, 0.f, 0.f, 0.f};
  f32x4 acc1 = (f32x4){0.f, 0.f, 0.f, 0.f};
  const int n0 = w * 32;
#pragma unroll 4
  for (int kt = 0; kt < 32; ++kt) {
    f16x8 a = A8[(size_t)(b0 + l15) * 128 + kt * 4 + l4];
    f16x8 bq0 = B8[(size_t)(n0 + l15) * 128 + kt * 4 + l4];
    f16x8 bq1 = B8[(size_t)(n0 + 16 + l15) * 128 + kt * 4 + l4];
    acc0 = __builtin_amdgcn_mfma_f32_16x16x32_f16(a, bq0, acc0, 0, 0, 0);
    acc1 = __builtin_amdgcn_mfma_f32_16x16x32_f16(a, bq1, acc1, 0, 0, 0);
  }
#pragma unroll
  for (int r = 0; r < 4; ++r) {
    int row = b0 + l4 * 4 + r;
    int col0 = n0 + l15;
    int col1 = n0 + 16 + l15;
    out[(size_t)row * 128 + col0] = sig_scaled(acc0[r]) + x[(size_t)row * 6400 + col0];
    out[(size_t)row * 128 + col1] = sig_scaled(acc1[r]) + x[(size_t)row * 6400 + col1];
  }
}

extern "C" void kernel_launch(void* const* d_in, const int* in_sizes, int n_in,
                              void* d_out, int out_size, void* d_ws, size_t ws_size,
                              hipStream_t stream) {
  const float* x  = (const float*)d_in[0];
  const float* Wq = (const float*)d_in[1];
  const float* Wk = (const float*)d_in[2];
  const float* Wv = (const float*)d_in[3];
  const float* Ws = (const float*)d_in[4];
  const float* O  = (const float*)d_in[5];
  float* out = (float*)d_out;

  unsigned short* ws16    = (unsigned short*)d_ws;
  unsigned short* WqT     = ws16;                    // 131072 elems
  unsigned short* WkT     = ws16 + 131072;
  unsigned short* WvT     = ws16 + 262144;
  unsigned short* OT      = ws16 + 393216;
  unsigned short* kw_all  = ws16 + 524288;           // 2048*1024 fp16
  unsigned short* res_all = ws16 + 524288 + 2097152; // 2048*1024 fp16

  prep_kernel<<<512, 256, 0, stream>>>(Wq, Wk, Wv, O, ws16);
  kw_kernel<<<dim3(32, 4), 256, 0, stream>>>(x, Ws, WkT, kw_all);
  fused_kernel<<<dim3(8, 2048 / GBATCH), 256, 0, stream>>>(x, WqT, WvT, kw_all, res_all);
  out_kernel<<<128, 256, 0, stream>>>(res_all, OT, x, out);
}

// Round 4
// 152.339 us; speedup vs baseline: 1.5217x; 1.5217x over previous
//
#include <hip/hip_runtime.h>
#include <hip/hip_bf16.h>

// Shapes (fixed): B=2048, S=50, D=128, H=8, L=128, HL=1024.
// R4: block = 1 batch (x read once), 4 waves; wave w owns heads {2w, 2w+1}
// entirely -> softmax is in-register per wave (no barrier, no LDS pass).
// Weight tiles stream from L2 with 1-deep register prefetch across a flat
// 32-tile sequence (Wq h0, Wv h0, Wq h1, Wv h1). One barrier per block.

typedef _Float16 f16x8 __attribute__((ext_vector_type(8)));
typedef float f32x4 __attribute__((ext_vector_type(4)));

#define LOG2E 1.44269504088896340736f

__device__ __forceinline__ unsigned short f2h(float f) {
  _Float16 h = (_Float16)f;
  return __builtin_bit_cast(unsigned short, h);
}
__device__ __forceinline__ float h2f(unsigned short s) {
  return (float)__builtin_bit_cast(_Float16, s);
}
__device__ __forceinline__ float fexp2(float x) {
#if __has_builtin(__builtin_amdgcn_exp2f)
  return __builtin_amdgcn_exp2f(x);
#else
  return exp2f(x);
#endif
}
__device__ __forceinline__ float frcp(float x) {
#if __has_builtin(__builtin_amdgcn_rcpf)
  return __builtin_amdgcn_rcpf(x);
#else
  return 1.0f / x;
#endif
}
__device__ __forceinline__ float sig_scaled(float a) {  // a = -log2e * z
  return frcp(1.0f + fexp2(a));
}

// ---------------------------------------------------------------------------
// prep: WqT/WkT/WvT [n=h*128+l][d] and OT [d][hl], all fp16, scaled by -log2e
// ---------------------------------------------------------------------------
__global__ void prep_kernel(const float* __restrict__ Wq, const float* __restrict__ Wk,
                            const float* __restrict__ Wv, const float* __restrict__ O,
                            unsigned short* __restrict__ ws16) {
  const float NS = -LOG2E;
  int tid = blockIdx.x * 256 + threadIdx.x;
  for (int j = tid; j < 4 * 131072; j += 512 * 256) {
    int which = j >> 17;
    int i = j & 131071;
    float val;
    if (which < 3) {
      const float* W = (which == 0) ? Wq : ((which == 1) ? Wk : Wv);
      int n = i >> 7, d = i & 127;
      int h = n >> 7, lidx = n & 127;
      val = W[h * 16384 + d * 128 + lidx];
    } else {
      int n = i >> 10, k = i & 1023;
      val = O[k * 128 + n];
    }
    ws16[j] = f2h(val * NS);
  }
}

// ---------------------------------------------------------------------------
// kw_all[b][n] = sigmoid(origin_b . Wk[:,n]) * Ws_flat[n]   (fp16)
// ---------------------------------------------------------------------------
__global__ __launch_bounds__(256, 2) void kw_kernel(
    const float* __restrict__ x, const float* __restrict__ Ws,
    const unsigned short* __restrict__ WkT, unsigned short* __restrict__ kw_all) {
  __shared__ __align__(16) char lds[16384];
  const int tid = threadIdx.x;
  const int b0 = blockIdx.x * 64;
  for (int i = tid; i < 2048; i += 256) {
    int row = i >> 5, c4 = i & 31;
    const float4 v = *(const float4*)(x + (size_t)(b0 + row) * 6400 + c4 * 4);
    uint2 pk;
    pk.x = (unsigned)f2h(v.x) | ((unsigned)f2h(v.y) << 16);
    pk.y = (unsigned)f2h(v.z) | ((unsigned)f2h(v.w) << 16);
    *(uint2*)(lds + row * 256 + ((c4 * 8) ^ ((row & 7) << 4))) = pk;
  }
  __syncthreads();
  const int w = tid >> 6, l = tid & 63, l15 = l & 15, l4 = l >> 4;
  f16x8 af[4][4];
#pragma unroll
  for (int mt = 0; mt < 4; ++mt)
#pragma unroll
    for (int kt = 0; kt < 4; ++kt) {
      int row = mt * 16 + l15;
      int c = kt * 64 + l4 * 16;
      af[mt][kt] = *(const f16x8*)(lds + row * 256 + (c ^ ((row & 7) << 4)));
    }
  const f16x8* B8 = (const f16x8*)WkT;
  for (int nt = 0; nt < 4; ++nt) {
    const int n0 = blockIdx.y * 256 + w * 64 + nt * 16;
    f16x8 bfr[4];
#pragma unroll
    for (int kt = 0; kt < 4; ++kt) bfr[kt] = B8[(size_t)(n0 + l15) * 16 + kt * 4 + l4];
    f32x4 acc[4];
#pragma unroll
    for (int mt = 0; mt < 4; ++mt) acc[mt] = (f32x4){0.f, 0.f, 0.f, 0.f};
#pragma unroll
    for (int mt = 0; mt < 4; ++mt)
#pragma unroll
      for (int kt = 0; kt < 4; ++kt)
        acc[mt] = __builtin_amdgcn_mfma_f32_16x16x32_f16(af[mt][kt], bfr[kt], acc[mt], 0, 0, 0);
    const float wsv = Ws[n0 + l15];
#pragma unroll
    for (int mt = 0; mt < 4; ++mt)
#pragma unroll
      for (int r = 0; r < 4; ++r) {
        int row = b0 + mt * 16 + l4 * 4 + r;
        kw_all[(size_t)row * 1024 + n0 + l15] = f2h(sig_scaled(acc[mt][r]) * wsv);
      }
  }
}

// ---------------------------------------------------------------------------
// fused: block = 1 batch. Wave w owns heads 2w,2w+1 (cols w*256..w*256+255).
// Flat 32-tile weight stream: [Wq h-lo nt0-7][Wv h-lo][Wq h-hi][Wv h-hi],
// 1-deep prefetch. Softmax fully in-register per wave. 1 barrier per block.
// ---------------------------------------------------------------------------
__global__ __launch_bounds__(256, 3) void fused_kernel(
    const float* __restrict__ x,
    const unsigned short* __restrict__ WqT, const unsigned short* __restrict__ WvT,
    const unsigned short* __restrict__ kw_all, unsigned short* __restrict__ res_all) {
  __shared__ __align__(16) char xlds[16384];
  __shared__ float kw_lds[1024];
  const int tid = threadIdx.x;
  const int b = blockIdx.x;
  const int w = tid >> 6, l = tid & 63, l15 = l & 15, l4 = l >> 4;

  // ---- stage x_b (fp16, XOR-swizzled, rows 50..63 zero) + kw ----
  const float* xb = x + (size_t)b * 6400;
#pragma unroll
  for (int j = 0; j < 8; ++j) {
    int idx = tid + j * 256;          // 0..2047 covers 64 rows x 32 float4
    int row = idx >> 5, c4 = idx & 31;
    uint2 pk = {0u, 0u};
    if (row < 50) {
      const float4 v = *(const float4*)(xb + row * 128 + c4 * 4);
      pk.x = (unsigned)f2h(v.x) | ((unsigned)f2h(v.y) << 16);
      pk.y = (unsigned)f2h(v.z) | ((unsigned)f2h(v.w) << 16);
    }
    *(uint2*)(xlds + row * 256 + ((c4 * 8) ^ ((row & 7) << 4))) = pk;
  }
  const unsigned short* kwb = kw_all + (size_t)b * 1024;
#pragma unroll
  for (int j = 0; j < 4; ++j) {
    int i = tid + j * 256;
    kw_lds[i] = h2f(kwb[i]);
  }
  __syncthreads();

  // ---- A-frags (x) register-resident for the whole block ----
  f16x8 af[4][4];
#pragma unroll
  for (int mt = 0; mt < 4; ++mt)
#pragma unroll
    for (int kt = 0; kt < 4; ++kt) {
      int row = mt * 16 + l15;
      int c = kt * 64 + l4 * 16;
      af[mt][kt] = *(const f16x8*)(xlds + row * 256 + (c ^ ((row & 7) << 4)));
    }

  // ---- flat 32-tile weight stream ----
  const f16x8* Bq = (const f16x8*)WqT;
  const f16x8* Bv = (const f16x8*)WvT;
  // tile t: base = (t>>3)&1 ? Bv : Bq ; nt = (t&7) + ((t>>4)<<3)
  f16x8 bcur[4], bnext[4];
  {
    const f16x8* p = Bq + (size_t)(w * 256 + l15) * 16;
#pragma unroll
    for (int kt = 0; kt < 4; ++kt) bcur[kt] = p[kt * 4 + l4];
  }
  float sAcc[4][4];
#pragma unroll
  for (int mt = 0; mt < 4; ++mt)
#pragma unroll
    for (int r = 0; r < 4; ++r) sAcc[mt][r] = 0.f;
  float at[4][4];

#pragma unroll
  for (int t = 0; t < 32; ++t) {
    const int nt = (t & 7) + ((t >> 4) << 3);
    if (t < 31) {
      const int t1 = t + 1;
      const int nt1 = (t1 & 7) + ((t1 >> 4) << 3);
      const f16x8* base = ((t1 >> 3) & 1) ? Bv : Bq;
      const f16x8* p = base + (size_t)(w * 256 + nt1 * 16 + l15) * 16;
#pragma unroll
      for (int kt = 0; kt < 4; ++kt) bnext[kt] = p[kt * 4 + l4];
    }
    f32x4 acc[4];
#pragma unroll
    for (int mt = 0; mt < 4; ++mt) acc[mt] = (f32x4){0.f, 0.f, 0.f, 0.f};
#pragma unroll
    for (int kt = 0; kt < 4; ++kt)
#pragma unroll
      for (int mt = 0; mt < 4; ++mt)
        acc[mt] = __builtin_amdgcn_mfma_f32_16x16x32_f16(af[mt][kt], bcur[kt], acc[mt], 0, 0, 0);

    if (((t >> 3) & 1) == 0) {
      // ---- Q phase: accumulate score partials ----
      const float kwv = kw_lds[w * 256 + nt * 16 + l15];
#pragma unroll
      for (int mt = 0; mt < 4; ++mt)
#pragma unroll
        for (int r = 0; r < 4; ++r)
          sAcc[mt][r] = fmaf(sig_scaled(acc[mt][r]), kwv, sAcc[mt][r]);
      if ((t & 7) == 7) {
        // reduce over the 16 cols spread across l15 lanes
#pragma unroll
        for (int mt = 0; mt < 4; ++mt)
#pragma unroll
          for (int r = 0; r < 4; ++r) {
            float v = sAcc[mt][r];
            v += __shfl_xor(v, 1);
            v += __shfl_xor(v, 2);
            v += __shfl_xor(v, 4);
            v += __shfl_xor(v, 8);
            at[mt][r] = v;          // score[row = mt*16 + l4*4 + r]
            sAcc[mt][r] = 0.f;
          }
        // in-register softmax over rows (mask rows >= 50)
        float m = -3.0e38f;
#pragma unroll
        for (int mt = 0; mt < 4; ++mt)
#pragma unroll
          for (int r = 0; r < 4; ++r) {
            int row = mt * 16 + l4 * 4 + r;
            m = fmaxf(m, (row < 50) ? at[mt][r] : -3.0e38f);
          }
        m = fmaxf(m, __shfl_xor(m, 16));
        m = fmaxf(m, __shfl_xor(m, 32));
        float tsum = 0.f;
#pragma unroll
        for (int mt = 0; mt < 4; ++mt)
#pragma unroll
          for (int r = 0; r < 4; ++r) {
            int row = mt * 16 + l4 * 4 + r;
            float e = (row < 50) ? fexp2((at[mt][r] - m) * LOG2E) : 0.f;
            at[mt][r] = e;
            tsum += e;
          }
        tsum += __shfl_xor(tsum, 16);
        tsum += __shfl_xor(tsum, 32);
        const float rs = frcp(tsum);
#pragma unroll
        for (int mt = 0; mt < 4; ++mt)
#pragma unroll
          for (int r = 0; r < 4; ++r) at[mt][r] *= rs;
      }
    } else {
      // ---- V phase: res[col] = sum_rows attn[row] * sigmoid(v[row,col]) ----
      float part = 0.f;
#pragma unroll
      for (int mt = 0; mt < 4; ++mt)
#pragma unroll
        for (int r = 0; r < 4; ++r)
          part = fmaf(at[mt][r], sig_scaled(acc[mt][r]), part);
      part += __shfl_xor(part, 16);
      part += __shfl_xor(part, 32);
      if (l4 == 0)
        res_all[(size_t)b * 1024 + w * 256 + nt * 16 + l15] = f2h(part);
    }
#pragma unroll
    for (int kt = 0; kt < 4; ++kt) bcur[kt] = bnext[kt];
  }
}

// ---------------------------------------------------------------------------
// out[b][d] = sigmoid(res[b,:] . O[:,d]) + x[b][0][d]
// ---------------------------------------------------------------------------
__global__ __launch_bounds__(256, 4) void out_kernel(
    const unsigned short* __restrict__ res_all, const unsigned short* __restrict__ OT,
    const float* __restrict__ x, float* __restrict__ out) {
  const int tid = threadIdx.x;
  const int w = tid >> 6, l = tid & 63, l15 = l & 15, l4 = l >> 4;
  const int b0 = blockIdx.x * 16;
  const f16x8* A8 = (const f16x8*)res_all;
  const f16x8* B8 = (const f16x8*)OT;
  f32x4 acc0 = (f32x4){0.f, 0.f, 0.f, 0.f};
  f32x4 acc1 = (f32x4){0.f, 0.f, 0.f, 0.f};
  const int n0 = w * 32;
#pragma unroll 4
  for (int kt = 0; kt < 32; ++kt) {
    f16x8 a = A8[(size_t)(b0 + l15) * 128 + kt * 4 + l4];
    f16x8 bq0 = B8[(size_t)(n0 + l15) * 128 + kt * 4 + l4];
    f16x8 bq1 = B8[(size_t)(n0 + 16 + l15) * 128 + kt * 4 + l4];
    acc0 = __builtin_amdgcn_mfma_f32_16x16x32_f16(a, bq0, acc0, 0, 0, 0);
    acc1 = __builtin_amdgcn_mfma_f32_16x16x32_f16(a, bq1, acc1, 0, 0, 0);
  }
#pragma unroll
  for (int r = 0; r < 4; ++r) {
    int row = b0 + l4 * 4 + r;
    int col0 = n0 + l15;
    int col1 = n0 + 16 + l15;
    out[(size_t)row * 128 + col0] = sig_scaled(acc0[r]) + x[(size_t)row * 6400 + col0];
    out[(size_t)row * 128 + col1] = sig_scaled(acc1[r]) + x[(size_t)row * 6400 + col1];
  }
}

extern "C" void kernel_launch(void* const* d_in, const int* in_sizes, int n_in,
                              void* d_out, int out_size, void* d_ws, size_t ws_size,
                              hipStream_t stream) {
  const float* x  = (const float*)d_in[0];
  const float* Wq = (const float*)d_in[1];
  const float* Wk = (const float*)d_in[2];
  const float* Wv = (const float*)d_in[3];
  const float* Ws = (const float*)d_in[4];
  const float* O  = (const float*)d_in[5];
  float* out = (float*)d_out;

  unsigned short* ws16    = (unsigned short*)d_ws;
  unsigned short* WqT     = ws16;                    // 131072 elems
  unsigned short* WkT     = ws16 + 131072;
  unsigned short* WvT     = ws16 + 262144;
  unsigned short* OT      = ws16 + 393216;
  unsigned short* kw_all  = ws16 + 524288;           // 2048*1024 fp16
  unsigned short* res_all = ws16 + 524288 + 2097152; // 2048*1024 fp16

  prep_kernel<<<512, 256, 0, stream>>>(Wq, Wk, Wv, O, ws16);
  kw_kernel<<<dim3(32, 4), 256, 0, stream>>>(x, Ws, WkT, kw_all);
  fused_kernel<<<2048, 256, 0, stream>>>(x, WqT, WvT, kw_all, res_all);
  out_kernel<<<128, 256, 0, stream>>>(res_all, OT, x, out);
}